// Round 4
// baseline (404.895 us; speedup 1.0000x reference)
//
#include <hip/hip_runtime.h>
#include <hip/hip_cooperative_groups.h>

namespace cg = cooperative_groups;

typedef unsigned int u32;
typedef unsigned long long u64;
typedef unsigned char u8;

#define NB 4
#define T_ANCH 261120
#define NCAND 2048          // candidates per image (4 levels x 512)
#define KSEL 512
#define POSTN 512
#define LOG_MAXF 4.135166556742356f
#define NMS_TH 0.7f
#define LVL_OFF_F 8192.0f
#define BINS 4096           // top-12 bits of mono32
#define EQCAP 8192          // tie-bin capacity (expected ~50-700 occupants)
#define GRID 256            // cooperative grid: 256 blocks x 1024 threads

__device__ __forceinline__ u32 mono32(float f){
  u32 u = __float_as_uint(f);
  return (u & 0x80000000u) ? ~u : (u | 0x80000000u);
}
__device__ __forceinline__ int lvl_hw(int lvl){ return 65536 >> (2*lvl); }
__device__ __forceinline__ int lvl_off(int lvl){
  return (lvl>0?196608:0) + (lvl>1?49152:0) + (lvl>2?12288:0);
}
// chunk-block mapping: bx in [0,256): b = bx>>6, c = bx&63
__device__ __forceinline__ void k1_map(int bx, int& b, int& lvl, int& ch){
  b = bx >> 6;
  int c = bx & 63;
  if (c < 48){ lvl = 0; ch = c; }
  else if (c < 60){ lvl = 1; ch = c - 48; }
  else if (c < 63){ lvl = 2; ch = c - 60; }
  else { lvl = 3; ch = 0; }
}

// ---------------------------------------------------------------------------
// rotated-quad intersection helpers
// ---------------------------------------------------------------------------
__device__ __forceinline__ void emit_pt(float* ox, float* oy, int oc, float x, float y){
  #pragma unroll
  for (int s = 0; s < 8; ++s) if (s == oc){ ox[s] = x; oy[s] = y; }
}

__device__ float quad_inter(const float* ca, const float* cb){
  float px[8], py[8];
  #pragma unroll
  for (int q = 0; q < 8; ++q){ px[q]=0.f; py[q]=0.f; }
  #pragma unroll
  for (int q = 0; q < 4; ++q){ px[q]=ca[2*q]; py[q]=ca[2*q+1]; }
  int cnt = 4;
  #pragma unroll
  for (int e = 0; e < 4; ++e){
    float p1x = cb[2*e],         p1y = cb[2*e+1];
    float p2x = cb[(2*e+2)&7],   p2y = cb[(2*e+3)&7];
    float ex = p2x-p1x, ey = p2y-p1y;
    float d[8];
    #pragma unroll
    for (int q = 0; q < 8; ++q) d[q] = ex*(py[q]-p1y) - ey*(px[q]-p1x);
    float ox[8], oy[8];
    #pragma unroll
    for (int q = 0; q < 8; ++q){ ox[q]=0.f; oy[q]=0.f; }
    int oc = 0;
    #pragma unroll
    for (int q = 0; q < 8; ++q){
      if (q < cnt){
        bool last = (q+1 >= cnt);
        float dn  = last ? d[0]  : d[(q+1)&7];
        bool in0 = (d[q] >= 0.0f), in1 = (dn >= 0.0f);
        if (in0){ emit_pt(ox,oy,oc,px[q],py[q]); oc++; }
        if (in0 != in1){
          float pnx = last ? px[0] : px[(q+1)&7];
          float pny = last ? py[0] : py[(q+1)&7];
          float den = d[q] - dn;
          float t = d[q] / ((den == 0.0f) ? 1.0f : den);
          emit_pt(ox,oy,oc, px[q] + t*(pnx-px[q]), py[q] + t*(pny-py[q]));
          oc++;
        }
      }
    }
    cnt = (oc > 8) ? 8 : oc;
    #pragma unroll
    for (int q = 0; q < 8; ++q){ px[q]=ox[q]; py[q]=oy[q]; }
  }
  if (cnt < 3) return 0.0f;
  float s = 0.0f;
  #pragma unroll
  for (int q = 0; q < 8; ++q){
    if (q < cnt){
      bool last = (q+1 >= cnt);
      float pnx = last ? px[0] : px[(q+1)&7];
      float pny = last ? py[0] : py[(q+1)&7];
      s += px[q]*pny - pnx*py[q];
    }
  }
  return 0.5f*fabsf(s);
}

// ---------------------------------------------------------------------------
// Mega-kernel args + union'd LDS (max member: P3 = 68 KB -> >=1 block/CU)
// ---------------------------------------------------------------------------
struct MegaArgs {
  const float *o0,*o1,*o2,*o3;
  const float *d0,*d1,*d2,*d3;
  const float *anchors;
  u32 *hist16, *gb0, *gcA, *emitc, *tiec;
  u64 *gtie;
  int *cand_j;
  float *cscore; u32 *csmono; u64 *ctb; float *cbox; u8 *cvalid;
  float *sscore, *sbox; u8 *svalid; float *geom; float4 *aabb4;
  u64 *maskp, *rowflag;
  float *out;
};

union SharedU {
  struct { u32 hist[BINS]; u32 coarse[64]; } p1;                       // 16.6 KB
  struct { u32 dbuf[KSEL]; u64 tbuf[4096]; u32 dn,tn,dbase,tbase; } p2;// 34 KB
  struct { u64 eq[EQCAP]; u32 wbuf[KSEL]; int jlist[KSEL]; u32 wn; } p3;// 68 KB
  struct { u32 sm[NCAND]; u64 stb[NCAND]; u32 cnt[32][32]; } p4;       // 28 KB
  struct { u32 lbuf[4096]; u32 lcnt; } p5;                             // 16 KB
  struct { u32 fid[NCAND]; u32 wcnt[32], wpref[32];
           u64 s_kept[32]; u32 pref[32]; u32 sF; } p6;                 // 8.8 KB
};

__global__ __launch_bounds__(1024) void mega(MegaArgs A)
{
  cg::grid_group grid = cg::this_grid();
  __shared__ SharedU sh;
  const int t = threadIdx.x;
  const int bx = blockIdx.x;
  const u64 gtid = (u64)bx*1024 + t;

  // ======================= P0: zero workspace regions ======================
  {
    // maskp: NB*NCAND*32 u64 = 262144 u64 -> exactly one per thread
    A.maskp[gtid] = 0ull;
    // hist16: 16*BINS u32 = 65536 -> first 64K threads
    if (gtid < (u64)16*BINS) A.hist16[gtid] = 0u;
    if (gtid < NB*32) A.rowflag[gtid] = 0ull;
    if (gtid < 16){ A.emitc[gtid] = 0u; A.tiec[gtid] = 0u; }
    // out: NB*POSTN*6 floats = 12288
    if (gtid < (u64)NB*POSTN*6) A.out[gtid] = 0.0f;
  }
  grid.sync();

  // ======================= P1: per-chunk histogram =========================
  {
    int b, lvl, ch;
    k1_map(bx, b, lvl, ch);
    int bid16 = b*4 + lvl;
    const float* ob = (lvl==0)?A.o0 : (lvl==1)?A.o1 : (lvl==2)?A.o2 : A.o3;
    int hw = lvl_hw(lvl);
    int size = 3*hw;
    int n4 = size >> 2;
    int i4 = ch*1024 + t;
    for (int i = t; i < BINS; i += 1024) sh.p1.hist[i] = 0;
    __syncthreads();
    if (i4 < n4){
      float4 v = ((const float4*)(ob + (size_t)b*size))[i4];
      atomicAdd(&sh.p1.hist[mono32(v.x) >> 20], 1u);
      atomicAdd(&sh.p1.hist[mono32(v.y) >> 20], 1u);
      atomicAdd(&sh.p1.hist[mono32(v.z) >> 20], 1u);
      atomicAdd(&sh.p1.hist[mono32(v.w) >> 20], 1u);
    }
    __syncthreads();
    u32* gh = A.hist16 + (size_t)bid16*BINS;
    for (int i = t; i < BINS; i += 1024){
      u32 c = sh.p1.hist[i];
      if (c) atomicAdd(&gh[i], c);
    }
  }
  grid.sync();

  // ======================= P1b: threshold walk (16 blocks) =================
  if (bx < 16){
    const u32* gh = A.hist16 + (size_t)bx*BINS;
    for (int i = t; i < BINS; i += 1024) sh.p1.hist[i] = gh[i];
    __syncthreads();
    if (t < 64){
      u32 s = 0;
      for (int z = 0; z < 64; ++z) s += sh.p1.hist[t*64 + z];
      sh.p1.coarse[t] = s;
    }
    __syncthreads();
    if (t == 0){
      u32 acc = 0;
      int cb = 63;
      while (acc + sh.p1.coarse[cb] < (u32)KSEL){ acc += sh.p1.coarse[cb]; --cb; }
      int z = cb*64 + 63;
      while (acc + sh.p1.hist[z] < (u32)KSEL){ acc += sh.p1.hist[z]; --z; }
      A.gb0[bx] = (u32)z;
      A.gcA[bx] = acc;
    }
  }
  grid.sync();

  // ======================= P2: classify ====================================
  {
    int b, lvl, ch;
    k1_map(bx, b, lvl, ch);
    int bid16 = b*4 + lvl;
    const float* ob = (lvl==0)?A.o0 : (lvl==1)?A.o1 : (lvl==2)?A.o2 : A.o3;
    int hw = lvl_hw(lvl);
    int size = 3*hw;
    int n4 = size >> 2;
    int i4 = ch*1024 + t;
    if (t == 0){ sh.p2.dn = 0; sh.p2.tn = 0; }
    __syncthreads();
    u32 b0v = A.gb0[bid16];
    if (i4 < n4){
      float4 v = ((const float4*)(ob + (size_t)b*size))[i4];
      int L = i4 << 2;
      int a = L / hw;                 // hw % 4 == 0 -> same a for all 4
      int pix = L - a*hw;
      int j0 = pix*3 + a;
      float vv[4] = {v.x, v.y, v.z, v.w};
      #pragma unroll
      for (int q = 0; q < 4; ++q){
        u32 m = mono32(vv[q]);
        u32 bin = m >> 20;
        int j = j0 + 3*q;
        if (bin > b0v){
          u32 s = atomicAdd(&sh.p2.dn, 1u);
          if (s < (u32)KSEL) sh.p2.dbuf[s] = (u32)j;
        } else if (bin == b0v){
          u32 s = atomicAdd(&sh.p2.tn, 1u);
          if (s < 4096u) sh.p2.tbuf[s] = ((u64)m << 32) | (u32)(~(u32)j);
        }
      }
    }
    __syncthreads();
    if (t == 0){
      sh.p2.dbase = sh.p2.dn ? atomicAdd(&A.emitc[bid16], sh.p2.dn) : 0u;
      sh.p2.tbase = sh.p2.tn ? atomicAdd(&A.tiec[bid16], sh.p2.tn) : 0u;
    }
    __syncthreads();
    for (u32 x = t; x < sh.p2.dn; x += 1024){
      u32 s = sh.p2.dbase + x;
      if (s < (u32)KSEL) A.cand_j[bid16*KSEL + s] = (int)sh.p2.dbuf[x];
    }
    for (u32 x = t; x < sh.p2.tn; x += 1024){
      u32 s = sh.p2.tbase + x;
      if (s < (u32)EQCAP) A.gtie[(size_t)bid16*EQCAP + s] = sh.p2.tbuf[x];
    }
  }
  grid.sync();

  // ======================= P3: tie rank-select + decode (16 blocks) ========
  if (bx < 16){
    int bid = bx;
    u32 n = A.tiec[bid]; if (n > (u32)EQCAP) n = (u32)EQCAP;
    u32 cA = A.gcA[bid];
    u32 k = (u32)KSEL - cA;
    if (t == 0) sh.p3.wn = 0;
    for (int i = t; i < KSEL; i += 1024) sh.p3.jlist[i] = 0;
    for (u32 i = t; i < n; i += 1024) sh.p3.eq[i] = A.gtie[(size_t)bid*EQCAP + i];
    __syncthreads();
    for (u32 i = t; i < n; i += 1024){
      u64 ki = sh.p3.eq[i];
      u32 r = 0;
      for (u32 m = 0; m < n; ++m) r += (sh.p3.eq[m] > ki) ? 1u : 0u;
      if (r < k){
        u32 s = atomicAdd(&sh.p3.wn, 1u);
        if (s < (u32)KSEL) sh.p3.wbuf[s] = (u32)(~(u32)ki);
      }
    }
    __syncthreads();
    u32 w = sh.p3.wn; if (w > (u32)KSEL) w = (u32)KSEL;
    for (u32 i = t; i < cA; i += 1024)
      if (i < (u32)KSEL) sh.p3.jlist[i] = A.cand_j[bid*KSEL + i];
    for (u32 x = t; x < w; x += 1024){
      u32 s = cA + x;
      if (s < (u32)KSEL) sh.p3.jlist[s] = (int)sh.p3.wbuf[x];
    }
    __syncthreads();

    if (t < KSEL){
      int c = bid*KSEL + t;
      int b = bid >> 2, lvl = bid & 3;
      int j = sh.p3.jlist[t];
      int hw = lvl_hw(lvl);
      u32 pix = (u32)j / 3u;
      u32 a = (u32)j - pix*3u;
      const float* ob = (lvl==0)?A.o0 : (lvl==1)?A.o1 : (lvl==2)?A.o2 : A.o3;
      const float* dl = (lvl==0)?A.d0 : (lvl==1)?A.d1 : (lvl==2)?A.d2 : A.d3;

      float ov = ob[(size_t)(b*3 + (int)a)*hw + pix];
      size_t dbase = ((size_t)(b*3 + (int)a)*6)*(size_t)hw + pix;
      float dx  = dl[dbase + 0*(size_t)hw];
      float dy  = dl[dbase + 1*(size_t)hw];
      float dw  = dl[dbase + 2*(size_t)hw];
      float dh  = dl[dbase + 3*(size_t)hw];
      float dsn = dl[dbase + 4*(size_t)hw];
      float dcs = dl[dbase + 5*(size_t)hw];
      int tt = lvl_off(lvl) + j;
      const float* an = A.anchors + ((size_t)b*T_ANCH + tt)*5;
      float ax=an[0], ay=an[1], aw=an[2], ah=an[3], aa=an[4];
      dw = fminf(dw, LOG_MAXF); dh = fminf(dh, LOG_MAXF);
      float cx = ax + dx*aw;
      float cy = ay + dy*ah;
      float ww = aw * expf(dw);
      float hh = ah * expf(dh);
      float ang = aa + atan2f(dsn, dcs);
      double sd = 1.0 / (1.0 + exp(-(double)ov));
      float sc = (float)sd;
      bool valid = (ww >= 1e-3f) && (hh >= 1e-3f) && (sc >= 0.0f);
      A.cscore[c] = sc;
      A.csmono[c] = valid ? mono32(sc) : 0u;    // invalid => -inf (stable by tb)
      // tiebreak: level asc, obj desc, idx asc (== reference positional order)
      A.ctb[c] = ((u64)lvl << 50) | ((u64)(u32)(~mono32(ov)) << 18) | (u64)(u32)j;
      A.cvalid[c] = valid ? 1 : 0;
      float* bb = A.cbox + (size_t)c*5;
      bb[0]=cx; bb[1]=cy; bb[2]=ww; bb[3]=hh; bb[4]=ang;
    }
  }
  grid.sync();

  // ======================= P4: rank-sort scatter ===========================
  {
    int b   = bx >> 6;                // image
    int blk = bx & 63;                // 64 blocks per image, 32 elems each
    for (int k2 = t; k2 < NCAND; k2 += 1024){
      sh.p4.sm[k2]  = A.csmono[b*NCAND + k2];
      sh.p4.stb[k2] = A.ctb[b*NCAND + k2];
    }
    __syncthreads();
    int esub = t >> 5;                // 0..31 element within block
    int ssub = t & 31;                // 0..31 scan slice
    int id = blk*32 + esub;
    u32 ms = sh.p4.sm[id];
    u64 mt = sh.p4.stb[id];
    u32 r = 0;
    #pragma unroll 8
    for (int it = 0; it < 64; ++it){
      int m = it*32 + ssub;
      u32 s2 = sh.p4.sm[m]; u64 t2 = sh.p4.stb[m];
      r += ((s2 > ms) || (s2 == ms && t2 < mt)) ? 1u : 0u;
    }
    sh.p4.cnt[esub][ssub] = r;
    __syncthreads();
    if (ssub == 0){
      u32 rank = 0;
      #pragma unroll
      for (int q = 0; q < 32; ++q) rank += sh.p4.cnt[esub][q];
      int gsrc = b*NCAND + id;
      int gdst = b*NCAND + (int)rank;
      A.sscore[gdst] = A.cscore[gsrc];
      A.svalid[gdst] = A.cvalid[gsrc];
      float b0 = A.cbox[(size_t)gsrc*5+0], b1 = A.cbox[(size_t)gsrc*5+1];
      float b2 = A.cbox[(size_t)gsrc*5+2], b3 = A.cbox[(size_t)gsrc*5+3];
      float b4 = A.cbox[(size_t)gsrc*5+4];
      float* sb = A.sbox + (size_t)gdst*5;
      sb[0]=b0; sb[1]=b1; sb[2]=b2; sb[3]=b3; sb[4]=b4;
      int lvl = (int)((mt >> 50) & 3ull);
      float offv = (float)lvl * LVL_OFF_F;
      float cx = b0 + offv, cy = b1 + offv, w=b2, h=b3, ang=b4;
      float cc = cosf(ang), sn = sinf(ang);
      float hx = 0.5f*w, hy = 0.5f*h;
      float x0 = cx + hx*cc - hy*sn, y0 = cy + hx*sn + hy*cc;
      float x1 = cx - hx*cc - hy*sn, y1 = cy - hx*sn + hy*cc;
      float x2 = cx - hx*cc + hy*sn, y2 = cy - hx*sn - hy*cc;
      float x3 = cx + hx*cc + hy*sn, y3 = cy + hx*sn - hy*cc;
      float minx = fminf(fminf(x0,x1),fminf(x2,x3));
      float maxx = fmaxf(fmaxf(x0,x1),fmaxf(x2,x3));
      float miny = fminf(fminf(y0,y1),fminf(y2,y3));
      float maxy = fmaxf(fmaxf(y0,y1),fmaxf(y2,y3));
      float* g = A.geom + (size_t)gdst*16;
      g[0]=minx; g[1]=maxx; g[2]=miny; g[3]=maxy; g[4]=w*h;
      g[5]=x0; g[6]=y0; g[7]=x1; g[8]=y1; g[9]=x2; g[10]=y2; g[11]=x3; g[12]=y3;
      A.aabb4[gdst] = make_float4(minx, maxx, miny, maxy);
    }
  }
  grid.sync();

  // ======================= P5: AABB filter + clip (2048 tasks) =============
  {
    int lane = t & 63;
    for (int task = bx; task < 2048; task += GRID){
      int img = task >> 9;
      int kk  = task & 511;
      __syncthreads();
      if (t == 0) sh.p5.lcnt = 0;
      __syncthreads();
      int rows[4] = {2*kk, 2*kk + 1, 2046 - 2*kk, 2047 - 2*kk};
      #pragma unroll
      for (int r = 0; r < 4; ++r){
        int i = rows[r];
        float4 gi = A.aabb4[img*NCAND + i];   // uniform -> cache broadcast
        for (int j = i + 1 + t; j < NCAND; j += 1024){
          float4 gj = A.aabb4[img*NCAND + j];
          bool pass = !(gi.x > gj.y || gj.x > gi.y || gi.z > gj.w || gj.z > gi.w);
          u64 bm = __ballot(pass);
          if (bm){
            int leader = __ffsll((long long)bm) - 1;
            u32 base = 0;
            if (lane == leader) base = atomicAdd(&sh.p5.lcnt, (u32)__popcll(bm));
            base = (u32)__shfl((int)base, leader);
            if (pass){
              u32 off = (u32)__popcll(bm & ((1ull << lane) - 1ull));
              sh.p5.lbuf[base + off] = (u32)((i << 11) | j);
            }
          }
        }
      }
      __syncthreads();
      u32 n = sh.p5.lcnt;
      for (u32 x = t; x < n; x += 1024){
        u32 gt = sh.p5.lbuf[x];
        int i = (int)(gt >> 11);
        int j = (int)(gt & (NCAND-1));
        const float* gi = A.geom + ((size_t)(img*NCAND + i))*16;
        const float* gj = A.geom + ((size_t)(img*NCAND + j))*16;
        float inter = quad_inter(gi+5, gj+5);
        float iou = inter / (gi[4] + gj[4] - inter + 1e-7f);
        if (iou > NMS_TH){
          atomicOr(&A.maskp[((size_t)(img*NCAND + i))*32 + (j >> 6)], 1ull << (j & 63));
          atomicOr(&A.rowflag[(size_t)img*32 + (i >> 6)], 1ull << (i & 63));
        }
      }
    }
  }
  grid.sync();

  // ======================= P6: greedy suppression + output (4 blocks) ======
  if (bx < NB){
    int b = bx;
    int wid = t >> 6, lane = t & 63;

    if (t < 32) sh.p6.wcnt[t] = (u32)__popcll(A.rowflag[b*32 + t]);
    __syncthreads();
    if (t == 0){
      u32 run = 0;
      for (int w = 0; w < 32; ++w){ sh.p6.wpref[w] = run; run += sh.p6.wcnt[w]; }
      sh.p6.sF = run;
    }
    __syncthreads();
    if (t < 32){
      u64 fw = A.rowflag[b*32 + t];
      u32 o = sh.p6.wpref[t];
      while (fw){
        int bpos = __builtin_ctzll(fw);
        sh.p6.fid[o++] = (u32)(t*64 + bpos);
        fw &= fw - 1;
      }
    }
    __syncthreads();

    if (wid == 0){
      u32 slo = 0, shi = 0;
      {
        int wl = lane & 31;
        u64 w = 0;
        for (int q = 0; q < 64; ++q)
          if (!A.svalid[b*NCAND + wl*64 + q]) w |= (1ull << q);
        slo = (u32)w; shi = (u32)(w >> 32);
      }
      u32 F = sh.p6.sF;
      const u64* mb = A.maskp + ((size_t)b*NCAND)*32;
      for (u32 f = 0; f < F; f += 8){
        u32 myfid = 0;
        if (f + (lane & 7) < F) myfid = sh.p6.fid[f + (lane & 7)];
        u64 v[8];
        #pragma unroll
        for (int q = 0; q < 8; ++q){
          if (f + q < F){
            u32 fq = (u32)__builtin_amdgcn_readlane((int)myfid, q);
            v[q] = mb[(size_t)fq*32 + (lane & 31)];
          } else v[q] = 0ull;
        }
        #pragma unroll
        for (int q = 0; q < 8; ++q){
          if (f + q < F){
            u32 i = (u32)__builtin_amdgcn_readlane((int)myfid, q);
            int wi = (int)(i >> 6);                  // wave-uniform
            u32 wlo = (u32)__builtin_amdgcn_readlane((int)slo, wi);
            u32 whi = (u32)__builtin_amdgcn_readlane((int)shi, wi);
            u64 w = ((u64)whi << 32) | wlo;
            u32 keep = (u32)((~w >> (i & 63)) & 1ull);
            u64 vm = v[q] & (0ull - (u64)keep);      // branchless
            slo |= (u32)vm; shi |= (u32)(vm >> 32);
          }
        }
      }
      if (lane < 32) sh.p6.s_kept[lane] = ~(((u64)shi << 32) | slo);
    }
    __syncthreads();

    if (t < 32) sh.p6.pref[t] = (u32)__popcll(sh.p6.s_kept[t]);
    __syncthreads();
    if (t == 0){
      u32 run = 0;
      for (int w = 0; w < 32; ++w){ u32 tv = sh.p6.pref[w]; sh.p6.pref[w] = run; run += tv; }
    }
    __syncthreads();
    for (int i = t; i < NCAND; i += 1024){
      u64 kw = sh.p6.s_kept[i >> 6];
      if ((kw >> (i & 63)) & 1ull){
        u32 rank = sh.p6.pref[i >> 6] + (u32)__popcll(kw & ((1ull << (i & 63)) - 1ull));
        if (rank < POSTN){
          const float* bp = A.sbox + ((size_t)(b*NCAND + i))*5;
          float* op = A.out + ((size_t)(b*POSTN + rank))*5;
          op[0]=bp[0]; op[1]=bp[1]; op[2]=bp[2]; op[3]=bp[3]; op[4]=bp[4];
          A.out[(size_t)NB*POSTN*5 + b*POSTN + rank] = A.sscore[b*NCAND + i];
        }
      }
    }
  }
}

// ---------------------------------------------------------------------------
extern "C" void kernel_launch(void* const* d_in, const int* in_sizes, int n_in,
                              void* d_out, int out_size, void* d_ws, size_t ws_size,
                              hipStream_t stream)
{
  (void)out_size; (void)ws_size;
  const float *obj[4] = {nullptr,nullptr,nullptr,nullptr};
  const float *dlt[4] = {nullptr,nullptr,nullptr,nullptr};
  const float *anchors = nullptr;
  for (int i = 0; i < n_in; ++i){
    int s = in_sizes[i];
    const float* p = (const float*)d_in[i];
    switch (s){
      case 786432:  obj[0] = p; break;
      case 4718592: dlt[0] = p; break;
      case 196608:  obj[1] = p; break;
      case 1179648: dlt[1] = p; break;
      case 49152:   obj[2] = p; break;
      case 294912:  dlt[2] = p; break;
      case 12288:   obj[3] = p; break;
      case 73728:   dlt[3] = p; break;
      case 5222400: anchors = p; break;
      default: break;
    }
  }

  char* wsb = (char*)d_ws;
  size_t off = 0;
  auto alloc = [&](size_t bytes)->void*{
    size_t cur = (off + 255) & ~(size_t)255;
    off = cur + bytes;
    return (void*)(wsb + cur);
  };
  MegaArgs A;
  A.o0 = obj[0]; A.o1 = obj[1]; A.o2 = obj[2]; A.o3 = obj[3];
  A.d0 = dlt[0]; A.d1 = dlt[1]; A.d2 = dlt[2]; A.d3 = dlt[3];
  A.anchors = anchors;
  A.cand_j = (int*)  alloc(16*KSEL*sizeof(int));
  A.cscore = (float*)alloc((size_t)NB*NCAND*sizeof(float));
  A.csmono = (u32*)  alloc((size_t)NB*NCAND*sizeof(u32));
  A.ctb    = (u64*)  alloc((size_t)NB*NCAND*sizeof(u64));
  A.cbox   = (float*)alloc((size_t)NB*NCAND*5*sizeof(float));
  A.cvalid = (u8*)   alloc((size_t)NB*NCAND);
  A.sscore = (float*)alloc((size_t)NB*NCAND*sizeof(float));
  A.sbox   = (float*)alloc((size_t)NB*NCAND*5*sizeof(float));
  A.svalid = (u8*)   alloc((size_t)NB*NCAND);
  A.geom   = (float*)alloc((size_t)NB*NCAND*16*sizeof(float));
  A.aabb4  = (float4*)alloc((size_t)NB*NCAND*sizeof(float4));
  A.gtie   = (u64*)  alloc((size_t)16*EQCAP*sizeof(u64));
  A.maskp  = (u64*)  alloc((size_t)NB*NCAND*32*sizeof(u64));
  A.rowflag= (u64*)  alloc((size_t)NB*32*sizeof(u64));
  A.hist16 = (u32*)  alloc((size_t)16*BINS*sizeof(u32));
  A.gb0    = (u32*)  alloc(16*sizeof(u32));
  A.gcA    = (u32*)  alloc(16*sizeof(u32));
  A.emitc  = (u32*)  alloc(16*sizeof(u32));
  A.tiec   = (u32*)  alloc(16*sizeof(u32));
  A.out    = (float*)d_out;

  void* kargs[] = { (void*)&A };
  hipLaunchCooperativeKernel((const void*)mega, dim3(GRID), dim3(1024),
                             kargs, 0, stream);
}

// Round 5
// 270.922 us; speedup vs baseline: 1.4945x; 1.4945x over previous
//
#include <hip/hip_runtime.h>

typedef unsigned int u32;
typedef unsigned long long u64;
typedef unsigned char u8;

#define NB 4
#define T_ANCH 261120
#define NCAND 2048          // candidates per image (4 levels x 512)
#define KSEL 512
#define POSTN 512
#define LOG_MAXF 4.135166556742356f
#define NMS_TH 0.7f
#define LVL_OFF_F 8192.0f
#define BINS 4096           // top-12 bits of mono32
#define EQCAP 8192          // tie-bin capacity (expected ~50-700 occupants)
#define K5_BLOCKS 2048      // 512 per image; 4 mirrored rows each -> 16 KB LDS
#define K1_BLOCKS 256       // 64 chunk-blocks per image (48/12/3/1 per level)

__device__ __forceinline__ u32 mono32(float f){
  u32 u = __float_as_uint(f);
  return (u & 0x80000000u) ? ~u : (u | 0x80000000u);
}
__device__ __forceinline__ int lvl_hw(int lvl){ return 65536 >> (2*lvl); }
__device__ __forceinline__ int lvl_off(int lvl){
  return (lvl>0?196608:0) + (lvl>1?49152:0) + (lvl>2?12288:0);
}
// chunk-block mapping: bx in [0,256): b = bx>>6, c = bx&63
__device__ __forceinline__ void k1_map(int bx, int& b, int& lvl, int& ch){
  b = bx >> 6;
  int c = bx & 63;
  if (c < 48){ lvl = 0; ch = c; }
  else if (c < 60){ lvl = 1; ch = c - 48; }
  else if (c < 63){ lvl = 2; ch = c - 60; }
  else { lvl = 3; ch = 0; }
}

// ---------------------------------------------------------------------------
// K123: hist (+last-block threshold walk) -> in-register classify (spin on
// published threshold; 256 blocks all resident: LDS 70KB -> 2 blocks/CU,
// capacity 512 >= grid 256) -> last-classify-block tie-select + decode.
// Cross-block traffic via agent-scope atomics (per-XCD L2 non-coherence).
// ---------------------------------------------------------------------------
union ShA {
  struct { u32 hist[BINS]; u32 coarse[64]; } a;                          // 16.6K
  struct { u32 dbuf[KSEL]; u64 tbuf[4096]; } c;                          // 34K
  struct { u64 eq[EQCAP]; u32 wbuf[KSEL]; int jlist[KSEL]; } p3;         // 69.6K
};

__global__ __launch_bounds__(1024) void k123(
    const float* __restrict__ o0, const float* __restrict__ o1,
    const float* __restrict__ o2, const float* __restrict__ o3,
    const float* __restrict__ d0, const float* __restrict__ d1,
    const float* __restrict__ d2, const float* __restrict__ d3,
    const float* __restrict__ anchors,
    u32* __restrict__ hist16, u32* __restrict__ done16,
    u32* __restrict__ pub16, u32* __restrict__ cls_done,
    u32* __restrict__ gb0, u32* __restrict__ gcA,
    u32* __restrict__ emitc, u32* __restrict__ tiec,
    int* __restrict__ cand_j, u64* __restrict__ gtie,
    float* __restrict__ cscore, u32* __restrict__ csmono,
    u64* __restrict__ ctb, float* __restrict__ cbox, u8* __restrict__ cvalid)
{
  __shared__ ShA sh;
  __shared__ int s_last, s_last2;
  __shared__ u32 s_b0, s_cA, s_dn, s_tn, s_dbase, s_tbase, s_wn;
  const int t = threadIdx.x;
  int b, lvl, ch;
  k1_map(blockIdx.x, b, lvl, ch);
  const int bid16 = b*4 + lvl;
  const int nch = (lvl==0?48 : lvl==1?12 : lvl==2?3 : 1);
  const float* ob = (lvl==0)?o0 : (lvl==1)?o1 : (lvl==2)?o2 : o3;
  const int hw = lvl_hw(lvl);
  const int size = 3*hw;
  const int n4 = size >> 2;
  const int i4 = ch*1024 + t;
  const bool has = (i4 < n4);

  // ---- phase A: load once into registers, LDS hist, global merge ----------
  u32 m0=0,m1=0,m2=0,m3=0;
  int j0 = 0;
  if (has){
    float4 v = ((const float4*)(ob + (size_t)b*size))[i4];
    m0 = mono32(v.x); m1 = mono32(v.y); m2 = mono32(v.z); m3 = mono32(v.w);
    int L = i4 << 2;
    int a = L / hw;                 // hw % 4 == 0 -> same a for all 4
    int pix = L - a*hw;
    j0 = pix*3 + a;
  }
  for (int i = t; i < BINS; i += 1024) sh.a.hist[i] = 0;
  __syncthreads();
  if (has){
    atomicAdd(&sh.a.hist[m0 >> 20], 1u);
    atomicAdd(&sh.a.hist[m1 >> 20], 1u);
    atomicAdd(&sh.a.hist[m2 >> 20], 1u);
    atomicAdd(&sh.a.hist[m3 >> 20], 1u);
  }
  __syncthreads();
  u32* gh = hist16 + (size_t)bid16*BINS;
  for (int i = t; i < BINS; i += 1024){
    u32 c = sh.a.hist[i];
    if (c) atomicAdd(&gh[i], c);
  }
  __syncthreads();
  if (t == 0){
    __threadfence();
    u32 d = atomicAdd(&done16[bid16], 1u);
    s_last = (d == (u32)(nch - 1)) ? 1 : 0;
  }
  __syncthreads();

  if (s_last){
    // merged hist -> threshold walk -> publish
    for (int i = t; i < BINS; i += 1024)
      sh.a.hist[i] = __hip_atomic_load(&gh[i], __ATOMIC_RELAXED, __HIP_MEMORY_SCOPE_AGENT);
    __syncthreads();
    if (t < 64){
      u32 s = 0;
      for (int z = 0; z < 64; ++z) s += sh.a.hist[t*64 + z];
      sh.a.coarse[t] = s;
    }
    __syncthreads();
    if (t == 0){
      u32 acc = 0;
      int cb = 63;
      while (acc + sh.a.coarse[cb] < (u32)KSEL){ acc += sh.a.coarse[cb]; --cb; }
      int z = cb*64 + 63;
      while (acc + sh.a.hist[z] < (u32)KSEL){ acc += sh.a.hist[z]; --z; }
      s_b0 = (u32)z; s_cA = acc;
      __hip_atomic_store(&gb0[bid16], (u32)z, __ATOMIC_RELAXED, __HIP_MEMORY_SCOPE_AGENT);
      __hip_atomic_store(&gcA[bid16], acc,   __ATOMIC_RELAXED, __HIP_MEMORY_SCOPE_AGENT);
      __threadfence();
      __hip_atomic_store(&pub16[bid16], 1u, __ATOMIC_RELEASE, __HIP_MEMORY_SCOPE_AGENT);
    }
  } else {
    if (t == 0){
      while (__hip_atomic_load(&pub16[bid16], __ATOMIC_ACQUIRE, __HIP_MEMORY_SCOPE_AGENT) == 0u)
        __builtin_amdgcn_s_sleep(2);
      s_b0 = __hip_atomic_load(&gb0[bid16], __ATOMIC_RELAXED, __HIP_MEMORY_SCOPE_AGENT);
      s_cA = __hip_atomic_load(&gcA[bid16], __ATOMIC_RELAXED, __HIP_MEMORY_SCOPE_AGENT);
    }
  }
  __syncthreads();
  const u32 b0v = s_b0;
  const u32 cA  = s_cA;
  __syncthreads();                    // LDS union: hist -> classify

  // ---- phase B: classify from registers -----------------------------------
  if (t == 0){ s_dn = 0; s_tn = 0; }
  __syncthreads();
  if (has){
    u32 mm[4] = {m0, m1, m2, m3};
    #pragma unroll
    for (int q = 0; q < 4; ++q){
      u32 m = mm[q];
      u32 bin = m >> 20;
      int j = j0 + 3*q;
      if (bin > b0v){
        u32 s = atomicAdd(&s_dn, 1u);
        if (s < (u32)KSEL) sh.c.dbuf[s] = (u32)j;
      } else if (bin == b0v){
        u32 s = atomicAdd(&s_tn, 1u);
        if (s < 4096u) sh.c.tbuf[s] = ((u64)m << 32) | (u32)(~(u32)j);
      }
    }
  }
  __syncthreads();
  if (t == 0){
    s_dbase = s_dn ? atomicAdd(&emitc[bid16], s_dn) : 0u;
    s_tbase = s_tn ? atomicAdd(&tiec[bid16], s_tn) : 0u;
  }
  __syncthreads();
  for (u32 x = t; x < s_dn; x += 1024){
    u32 s = s_dbase + x;
    if (s < (u32)KSEL)
      __hip_atomic_store(&cand_j[bid16*KSEL + s], (int)sh.c.dbuf[x],
                         __ATOMIC_RELAXED, __HIP_MEMORY_SCOPE_AGENT);
  }
  for (u32 x = t; x < s_tn; x += 1024){
    u32 s = s_tbase + x;
    if (s < (u32)EQCAP)
      __hip_atomic_store(&gtie[(size_t)bid16*EQCAP + s], sh.c.tbuf[x],
                         __ATOMIC_RELAXED, __HIP_MEMORY_SCOPE_AGENT);
  }
  __syncthreads();
  if (t == 0){
    __threadfence();
    u32 d = __hip_atomic_fetch_add(&cls_done[bid16], 1u,
                                   __ATOMIC_ACQ_REL, __HIP_MEMORY_SCOPE_AGENT);
    s_last2 = (d == (u32)(nch - 1)) ? 1 : 0;
  }
  __syncthreads();
  if (!s_last2) return;

  // ---- phase C: tie rank-select + decode (last classify-block only) -------
  u32 n = __hip_atomic_load(&tiec[bid16], __ATOMIC_RELAXED, __HIP_MEMORY_SCOPE_AGENT);
  if (n > (u32)EQCAP) n = (u32)EQCAP;
  u32 k = (u32)KSEL - cA;
  if (t == 0) s_wn = 0;
  __syncthreads();                    // LDS union: classify -> p3
  for (int i = t; i < KSEL; i += 1024) sh.p3.jlist[i] = 0;
  for (u32 i = t; i < n; i += 1024)
    sh.p3.eq[i] = __hip_atomic_load(&gtie[(size_t)bid16*EQCAP + i],
                                    __ATOMIC_RELAXED, __HIP_MEMORY_SCOPE_AGENT);
  __syncthreads();
  for (u32 i = t; i < n; i += 1024){
    u64 ki = sh.p3.eq[i];
    u32 r = 0;
    for (u32 m = 0; m < n; ++m) r += (sh.p3.eq[m] > ki) ? 1u : 0u;
    if (r < k){
      u32 s = atomicAdd(&s_wn, 1u);
      if (s < (u32)KSEL) sh.p3.wbuf[s] = (u32)(~(u32)ki);
    }
  }
  __syncthreads();
  u32 w = s_wn; if (w > (u32)KSEL) w = (u32)KSEL;
  for (u32 i = t; i < cA; i += 1024)
    if (i < (u32)KSEL)
      sh.p3.jlist[i] = __hip_atomic_load(&cand_j[bid16*KSEL + i],
                                         __ATOMIC_RELAXED, __HIP_MEMORY_SCOPE_AGENT);
  for (u32 x = t; x < w; x += 1024){
    u32 s = cA + x;
    if (s < (u32)KSEL) sh.p3.jlist[s] = (int)sh.p3.wbuf[x];
  }
  __syncthreads();

  if (t < KSEL){
    int c = bid16*KSEL + t;
    int j = sh.p3.jlist[t];
    u32 pix = (u32)j / 3u;
    u32 a = (u32)j - pix*3u;
    const float* dl = (lvl==0)?d0 : (lvl==1)?d1 : (lvl==2)?d2 : d3;
    float ov = ob[(size_t)(b*3 + (int)a)*hw + pix];
    size_t dbase = ((size_t)(b*3 + (int)a)*6)*(size_t)hw + pix;
    float dx  = dl[dbase + 0*(size_t)hw];
    float dy  = dl[dbase + 1*(size_t)hw];
    float dw  = dl[dbase + 2*(size_t)hw];
    float dh  = dl[dbase + 3*(size_t)hw];
    float dsn = dl[dbase + 4*(size_t)hw];
    float dcs = dl[dbase + 5*(size_t)hw];
    int tt = lvl_off(lvl) + j;
    const float* an = anchors + ((size_t)b*T_ANCH + tt)*5;
    float ax=an[0], ay=an[1], aw=an[2], ah=an[3], aa=an[4];
    dw = fminf(dw, LOG_MAXF); dh = fminf(dh, LOG_MAXF);
    float cx = ax + dx*aw;
    float cy = ay + dy*ah;
    float ww = aw * expf(dw);
    float hh = ah * expf(dh);
    float ang = aa + atan2f(dsn, dcs);
    double sd = 1.0 / (1.0 + exp(-(double)ov));
    float sc = (float)sd;
    bool valid = (ww >= 1e-3f) && (hh >= 1e-3f) && (sc >= 0.0f);
    cscore[c] = sc;
    csmono[c] = valid ? mono32(sc) : 0u;      // invalid => -inf (stable by tb)
    // tiebreak: level asc, obj desc, idx asc (== reference positional order)
    ctb[c] = ((u64)lvl << 50) | ((u64)(u32)(~mono32(ov)) << 18) | (u64)(u32)j;
    cvalid[c] = valid ? 1 : 0;
    float* bb = cbox + (size_t)c*5;
    bb[0]=cx; bb[1]=cy; bb[2]=ww; bb[3]=hh; bb[4]=ang;
  }
}

// ---------------------------------------------------------------------------
// K4: per-image exact RANK-SORT scatter over 256 blocks. Also zeroes the
// mask/rowflag region (stream-ordered before K56 needs it).
// ---------------------------------------------------------------------------
__global__ __launch_bounds__(256) void k4_rank(
    const u32* __restrict__ csmono, const u64* __restrict__ ctb,
    const float* __restrict__ cscore, const float* __restrict__ cbox,
    const u8* __restrict__ cvalid,
    float* __restrict__ sscore, float* __restrict__ sbox,
    float* __restrict__ geom, float4* __restrict__ aabb4,
    u8* __restrict__ svalid, u64* __restrict__ maskz, u64* __restrict__ rowflagz)
{
  int b   = blockIdx.x >> 6;          // image
  int blk = blockIdx.x & 63;          // 64 blocks per image, 32 elems each
  __shared__ u32 sm[NCAND];
  __shared__ u64 stb[NCAND];
  __shared__ u32 cnt[32][8];
  // zero 8 KB slice of mask (total NB*NCAND*32 u64 = 262144 = 256 blocks*1024)
  {
    u64* mz = maskz + (size_t)blockIdx.x * 1024;
    for (int x = threadIdx.x; x < 1024; x += 256) mz[x] = 0ull;
    if (threadIdx.x == 0 && blockIdx.x < NB*32) rowflagz[blockIdx.x] = 0ull;
  }
  for (int k = threadIdx.x; k < NCAND; k += 256){
    sm[k]  = csmono[b*NCAND + k];
    stb[k] = ctb[b*NCAND + k];
  }
  __syncthreads();
  int esub = threadIdx.x >> 3;        // 0..31 element within block
  int ssub = threadIdx.x & 7;         // 0..7 scan slice
  int id = blk*32 + esub;
  u32 ms = sm[id];
  u64 mt = stb[id];
  u32 r = 0;
  #pragma unroll 8
  for (int it = 0; it < 256; ++it){
    int m = it*8 + ssub;
    u32 s2 = sm[m]; u64 t2 = stb[m];
    r += ((s2 > ms) || (s2 == ms && t2 < mt)) ? 1u : 0u;
  }
  cnt[esub][ssub] = r;
  __syncthreads();
  if (ssub == 0){
    u32 rank = 0;
    #pragma unroll
    for (int q = 0; q < 8; ++q) rank += cnt[esub][q];
    int gsrc = b*NCAND + id;
    int gdst = b*NCAND + (int)rank;
    sscore[gdst] = cscore[gsrc];
    svalid[gdst] = cvalid[gsrc];
    float b0 = cbox[(size_t)gsrc*5+0], b1 = cbox[(size_t)gsrc*5+1];
    float b2 = cbox[(size_t)gsrc*5+2], b3 = cbox[(size_t)gsrc*5+3];
    float b4 = cbox[(size_t)gsrc*5+4];
    float* sb = sbox + (size_t)gdst*5;
    sb[0]=b0; sb[1]=b1; sb[2]=b2; sb[3]=b3; sb[4]=b4;
    int lvl = (int)((mt >> 50) & 3ull);
    float offv = (float)lvl * LVL_OFF_F;
    float cx = b0 + offv, cy = b1 + offv, w=b2, h=b3, ang=b4;
    float cc = cosf(ang), sn = sinf(ang);
    float hx = 0.5f*w, hy = 0.5f*h;
    float x0 = cx + hx*cc - hy*sn, y0 = cy + hx*sn + hy*cc;
    float x1 = cx - hx*cc - hy*sn, y1 = cy - hx*sn + hy*cc;
    float x2 = cx - hx*cc + hy*sn, y2 = cy - hx*sn - hy*cc;
    float x3 = cx + hx*cc + hy*sn, y3 = cy + hx*sn - hy*cc;
    float minx = fminf(fminf(x0,x1),fminf(x2,x3));
    float maxx = fmaxf(fmaxf(x0,x1),fmaxf(x2,x3));
    float miny = fminf(fminf(y0,y1),fminf(y2,y3));
    float maxy = fmaxf(fmaxf(y0,y1),fmaxf(y2,y3));
    float* g = geom + (size_t)gdst*16;
    g[0]=minx; g[1]=maxx; g[2]=miny; g[3]=maxy; g[4]=w*h;
    g[5]=x0; g[6]=y0; g[7]=x1; g[8]=y1; g[9]=x2; g[10]=y2; g[11]=x3; g[12]=y3;
    aabb4[gdst] = make_float4(minx, maxx, miny, maxy);
  }
}

// ---------------------------------------------------------------------------
// K56: mirrored-row AABB filter -> LDS pair list -> inline clip + IoU +
// scatter bits; then the LAST block of each image (acq-rel done-counter)
// runs the greedy suppression + output for that image inline.
// ---------------------------------------------------------------------------
__device__ __forceinline__ void emit_pt(float* ox, float* oy, int oc, float x, float y){
  #pragma unroll
  for (int s = 0; s < 8; ++s) if (s == oc){ ox[s] = x; oy[s] = y; }
}

__device__ float quad_inter(const float* ca, const float* cb){
  float px[8], py[8];
  #pragma unroll
  for (int q = 0; q < 8; ++q){ px[q]=0.f; py[q]=0.f; }
  #pragma unroll
  for (int q = 0; q < 4; ++q){ px[q]=ca[2*q]; py[q]=ca[2*q+1]; }
  int cnt = 4;
  #pragma unroll
  for (int e = 0; e < 4; ++e){
    float p1x = cb[2*e],         p1y = cb[2*e+1];
    float p2x = cb[(2*e+2)&7],   p2y = cb[(2*e+3)&7];
    float ex = p2x-p1x, ey = p2y-p1y;
    float d[8];
    #pragma unroll
    for (int q = 0; q < 8; ++q) d[q] = ex*(py[q]-p1y) - ey*(px[q]-p1x);
    float ox[8], oy[8];
    #pragma unroll
    for (int q = 0; q < 8; ++q){ ox[q]=0.f; oy[q]=0.f; }
    int oc = 0;
    #pragma unroll
    for (int q = 0; q < 8; ++q){
      if (q < cnt){
        bool last = (q+1 >= cnt);
        float dn  = last ? d[0]  : d[(q+1)&7];
        bool in0 = (d[q] >= 0.0f), in1 = (dn >= 0.0f);
        if (in0){ emit_pt(ox,oy,oc,px[q],py[q]); oc++; }
        if (in0 != in1){
          float pnx = last ? px[0] : px[(q+1)&7];
          float pny = last ? py[0] : py[(q+1)&7];
          float den = d[q] - dn;
          float t = d[q] / ((den == 0.0f) ? 1.0f : den);
          emit_pt(ox,oy,oc, px[q] + t*(pnx-px[q]), py[q] + t*(pny-py[q]));
          oc++;
        }
      }
    }
    cnt = (oc > 8) ? 8 : oc;
    #pragma unroll
    for (int q = 0; q < 8; ++q){ px[q]=ox[q]; py[q]=oy[q]; }
  }
  if (cnt < 3) return 0.0f;
  float s = 0.0f;
  #pragma unroll
  for (int q = 0; q < 8; ++q){
    if (q < cnt){
      bool last = (q+1 >= cnt);
      float pnx = last ? px[0] : px[(q+1)&7];
      float pny = last ? py[0] : py[(q+1)&7];
      s += px[q]*pny - pnx*py[q];
    }
  }
  return 0.5f*fabsf(s);
}

union Sh56 {
  struct { u32 lbuf[4096]; } a;                                          // 16K
  struct { u32 fid[NCAND]; u64 rfw[32]; u32 wcnt[32], wpref[32];
           u64 s_kept[32]; u32 pref[32]; u32 sF; } b;                    // 9.2K
};

__global__ __launch_bounds__(256) void k56_pairs_out(
    const float4* __restrict__ aabb4, const float* __restrict__ geom,
    u64* __restrict__ mask, u64* __restrict__ rowflag,
    u32* __restrict__ clipdone,
    const u8* __restrict__ svalid,
    const float* __restrict__ sbox, const float* __restrict__ sscore,
    float* __restrict__ out)
{
  __shared__ Sh56 sh;
  __shared__ u32 s_lcnt;
  __shared__ int s_w;
  const int t = threadIdx.x;
  if (t == 0) s_lcnt = 0;
  __syncthreads();
  int img = blockIdx.x >> 9;             // 512 blocks per image
  int kk  = blockIdx.x & 511;
  int lane = t & 63;
  int rows[4] = {2*kk, 2*kk + 1, 2046 - 2*kk, 2047 - 2*kk};
  #pragma unroll
  for (int r = 0; r < 4; ++r){
    int i = rows[r];
    float4 gi = aabb4[img*NCAND + i];    // uniform -> cache broadcast
    for (int j = i + 1 + t; j < NCAND; j += 256){
      float4 gj = aabb4[img*NCAND + j];
      bool pass = !(gi.x > gj.y || gj.x > gi.y || gi.z > gj.w || gj.z > gi.w);
      u64 bm = __ballot(pass);
      if (bm){
        int leader = __ffsll((long long)bm) - 1;
        u32 base = 0;
        if (lane == leader) base = atomicAdd(&s_lcnt, (u32)__popcll(bm));
        base = (u32)__shfl((int)base, leader);
        if (pass){
          u32 off = (u32)__popcll(bm & ((1ull << lane) - 1ull));
          sh.a.lbuf[base + off] = (u32)((i << 11) | j);
        }
      }
    }
  }
  __syncthreads();
  u32 n = s_lcnt;
  for (u32 x = t; x < n; x += 256){
    u32 gt = sh.a.lbuf[x];
    int i = (int)(gt >> 11);
    int j = (int)(gt & (NCAND-1));
    const float* gi = geom + ((size_t)(img*NCAND + i))*16;
    const float* gj = geom + ((size_t)(img*NCAND + j))*16;
    float inter = quad_inter(gi+5, gj+5);
    float iou = inter / (gi[4] + gj[4] - inter + 1e-7f);
    if (iou > NMS_TH){
      atomicOr(&mask[((size_t)(img*NCAND + i))*32 + (j >> 6)], 1ull << (j & 63));
      atomicOr(&rowflag[(size_t)img*32 + (i >> 6)], 1ull << (i & 63));
    }
  }
  __syncthreads();
  if (t == 0){
    __threadfence();
    u32 d = __hip_atomic_fetch_add(&clipdone[img], 1u,
                                   __ATOMIC_ACQ_REL, __HIP_MEMORY_SCOPE_AGENT);
    s_w = (d == 511u) ? 1 : 0;
  }
  __syncthreads();
  if (!s_w) return;

  // ---- last block of this image: greedy suppression + output --------------
  const int b = img;
  __syncthreads();                      // LDS union: lbuf -> walk structures
  if (t < 32)
    sh.b.rfw[t] = __hip_atomic_load(&rowflag[b*32 + t],
                                    __ATOMIC_RELAXED, __HIP_MEMORY_SCOPE_AGENT);
  __syncthreads();
  if (t < 32) sh.b.wcnt[t] = (u32)__popcll(sh.b.rfw[t]);
  __syncthreads();
  if (t == 0){
    u32 run = 0;
    for (int w = 0; w < 32; ++w){ sh.b.wpref[w] = run; run += sh.b.wcnt[w]; }
    sh.b.sF = run;
  }
  __syncthreads();
  if (t < 32){
    u64 fw = sh.b.rfw[t];
    u32 o = sh.b.wpref[t];
    while (fw){
      int bpos = __builtin_ctzll(fw);
      sh.b.fid[o++] = (u32)(t*64 + bpos);
      fw &= fw - 1;
    }
  }
  // zero-fill this image's output slice
  for (int x = t; x < POSTN*5; x += 256) out[(size_t)b*POSTN*5 + x] = 0.0f;
  for (int x = t; x < POSTN;   x += 256) out[(size_t)NB*POSTN*5 + b*POSTN + x] = 0.0f;
  __syncthreads();

  if ((t >> 6) == 0){
    // sup init from svalid: lane l<32 builds word l (lanes 32-63 mirror)
    u32 slo = 0, shi = 0;
    {
      int wl = lane & 31;
      u64 w = 0;
      for (int q = 0; q < 64; ++q)
        if (!svalid[b*NCAND + wl*64 + q]) w |= (1ull << q);
      slo = (u32)w; shi = (u32)(w >> 32);
    }
    u32 F = sh.b.sF;
    const u64* mb = mask + ((size_t)b*NCAND)*32;
    for (u32 f = 0; f < F; f += 8){
      u32 myfid = 0;
      if (f + (lane & 7) < F) myfid = sh.b.fid[f + (lane & 7)];
      u64 v[8];
      #pragma unroll
      for (int q = 0; q < 8; ++q){
        if (f + q < F){
          u32 fq = (u32)__builtin_amdgcn_readlane((int)myfid, q);
          v[q] = __hip_atomic_load(&mb[(size_t)fq*32 + (lane & 31)],
                                   __ATOMIC_RELAXED, __HIP_MEMORY_SCOPE_AGENT);
        } else v[q] = 0ull;
      }
      #pragma unroll
      for (int q = 0; q < 8; ++q){
        if (f + q < F){
          u32 i = (u32)__builtin_amdgcn_readlane((int)myfid, q);
          int wi = (int)(i >> 6);                  // wave-uniform
          u32 wlo = (u32)__builtin_amdgcn_readlane((int)slo, wi);
          u32 whi = (u32)__builtin_amdgcn_readlane((int)shi, wi);
          u64 w = ((u64)whi << 32) | wlo;
          u32 keep = (u32)((~w >> (i & 63)) & 1ull);
          u64 vm = v[q] & (0ull - (u64)keep);      // branchless
          slo |= (u32)vm; shi |= (u32)(vm >> 32);
        }
      }
    }
    if (lane < 32) sh.b.s_kept[lane] = ~(((u64)shi << 32) | slo);
  }
  __syncthreads();

  if (t < 32) sh.b.pref[t] = (u32)__popcll(sh.b.s_kept[t]);
  __syncthreads();
  if (t == 0){
    u32 run = 0;
    for (int w = 0; w < 32; ++w){ u32 tv = sh.b.pref[w]; sh.b.pref[w] = run; run += tv; }
  }
  __syncthreads();
  for (int i = t; i < NCAND; i += 256){
    u64 kw = sh.b.s_kept[i >> 6];
    if ((kw >> (i & 63)) & 1ull){
      u32 rank = sh.b.pref[i >> 6] + (u32)__popcll(kw & ((1ull << (i & 63)) - 1ull));
      if (rank < POSTN){
        const float* bp = sbox + ((size_t)(b*NCAND + i))*5;
        float* op = out + ((size_t)(b*POSTN + rank))*5;
        op[0]=bp[0]; op[1]=bp[1]; op[2]=bp[2]; op[3]=bp[3]; op[4]=bp[4];
        out[(size_t)NB*POSTN*5 + b*POSTN + rank] = sscore[b*NCAND + i];
      }
    }
  }
}

// ---------------------------------------------------------------------------
extern "C" void kernel_launch(void* const* d_in, const int* in_sizes, int n_in,
                              void* d_out, int out_size, void* d_ws, size_t ws_size,
                              hipStream_t stream)
{
  (void)out_size; (void)ws_size;
  const float *obj[4] = {nullptr,nullptr,nullptr,nullptr};
  const float *dlt[4] = {nullptr,nullptr,nullptr,nullptr};
  const float *anchors = nullptr;
  for (int i = 0; i < n_in; ++i){
    int s = in_sizes[i];
    const float* p = (const float*)d_in[i];
    switch (s){
      case 786432:  obj[0] = p; break;
      case 4718592: dlt[0] = p; break;
      case 196608:  obj[1] = p; break;
      case 1179648: dlt[1] = p; break;
      case 49152:   obj[2] = p; break;
      case 294912:  dlt[2] = p; break;
      case 12288:   obj[3] = p; break;
      case 73728:   dlt[3] = p; break;
      case 5222400: anchors = p; break;
      default: break;
    }
  }

  char* wsb = (char*)d_ws;
  size_t off = 0;
  auto alloc = [&](size_t bytes)->void*{
    size_t cur = (off + 255) & ~(size_t)255;
    off = cur + bytes;
    return (void*)(wsb + cur);
  };
  int*   cand_j = (int*)  alloc(16*KSEL*sizeof(int));
  float* cscore = (float*)alloc((size_t)NB*NCAND*sizeof(float));
  u32*   csmono = (u32*)  alloc((size_t)NB*NCAND*sizeof(u32));
  u64*   ctb    = (u64*)  alloc((size_t)NB*NCAND*sizeof(u64));
  float* cbox   = (float*)alloc((size_t)NB*NCAND*5*sizeof(float));
  u8*    cvalid = (u8*)   alloc((size_t)NB*NCAND);
  float* sscore = (float*)alloc((size_t)NB*NCAND*sizeof(float));
  float* sbox   = (float*)alloc((size_t)NB*NCAND*5*sizeof(float));
  u8*    svalid = (u8*)   alloc((size_t)NB*NCAND);
  float* geom   = (float*)alloc((size_t)NB*NCAND*16*sizeof(float));
  float4* aabb4 = (float4*)alloc((size_t)NB*NCAND*sizeof(float4));
  u64*   gtie   = (u64*)  alloc((size_t)16*EQCAP*sizeof(u64));
  u64*   maskp  = (u64*)  alloc((size_t)NB*NCAND*32*sizeof(u64));   // zeroed by k4
  u64*   rowflag= (u64*)  alloc((size_t)NB*32*sizeof(u64));         // zeroed by k4
  u32*   gb0    = (u32*)  alloc(16*sizeof(u32));
  u32*   gcA    = (u32*)  alloc(16*sizeof(u32));
  // ---- contiguous zero region (memset) -----------------------------------
  u32*   hist16 = (u32*)  alloc((size_t)16*BINS*sizeof(u32));
  u32*   done16 = (u32*)  alloc(16*sizeof(u32));
  u32*   pub16  = (u32*)  alloc(16*sizeof(u32));
  u32*   clsdn  = (u32*)  alloc(16*sizeof(u32));
  u32*   clipdn = (u32*)  alloc(NB*sizeof(u32));
  u32*   emitc  = (u32*)  alloc(16*sizeof(u32));
  u32*   tiec   = (u32*)  alloc(16*sizeof(u32));
  size_t zero_len = (size_t)((wsb + off) - (char*)hist16);

  hipMemsetAsync(hist16, 0, zero_len, stream);

  hipLaunchKernelGGL(k123, dim3(K1_BLOCKS), dim3(1024), 0, stream,
                     obj[0], obj[1], obj[2], obj[3],
                     dlt[0], dlt[1], dlt[2], dlt[3], anchors,
                     hist16, done16, pub16, clsdn, gb0, gcA, emitc, tiec,
                     cand_j, gtie, cscore, csmono, ctb, cbox, cvalid);
  hipLaunchKernelGGL(k4_rank, dim3(256), dim3(256), 0, stream,
                     csmono, ctb, cscore, cbox, cvalid, sscore, sbox, geom,
                     aabb4, svalid, maskp, rowflag);
  hipLaunchKernelGGL(k56_pairs_out, dim3(K5_BLOCKS), dim3(256), 0, stream,
                     aabb4, geom, maskp, rowflag, clipdn,
                     svalid, sbox, sscore, (float*)d_out);
}